// Round 1
// baseline (1054.942 us; speedup 1.0000x reference)
//
#include <hip/hip_runtime.h>

#define NB   8192
#define NF   2048
#define NC   345
#define NCP  384
#define EPSV 1e-5f

typedef __bf16 bf16x8 __attribute__((ext_vector_type(8)));
typedef float  f32x4  __attribute__((ext_vector_type(4)));

__device__ __forceinline__ float bs2f(unsigned int u) { return __uint_as_float(u << 16); }
__device__ __forceinline__ unsigned short f2bs(float f) {
    unsigned int u = __float_as_uint(f);
    u += 0x7fffu + ((u >> 16) & 1u);   // round-to-nearest-even
    return (unsigned short)(u >> 16);
}

#define GLD16(g, l)                                                                     \
    __builtin_amdgcn_global_load_lds((const __attribute__((address_space(1))) void*)(g),\
                                     (__attribute__((address_space(3))) void*)(l),      \
                                     16, 0, 0)

// ---------------- gather + cast x rows: xg[i] = bf16(x[order[i]]) ----------------
__global__ void k_gather(const float* __restrict__ x, const int* __restrict__ order,
                         unsigned short* __restrict__ xg) {
    const int row = blockIdx.x;
    const long src = order[row];
    const float4* xr = (const float4*)(x + src * 2048);
    float4 a = xr[threadIdx.x * 2 + 0];
    float4 b = xr[threadIdx.x * 2 + 1];
    uint4 o;
    o.x = (unsigned)f2bs(a.x) | ((unsigned)f2bs(a.y) << 16);
    o.y = (unsigned)f2bs(a.z) | ((unsigned)f2bs(a.w) << 16);
    o.z = (unsigned)f2bs(b.x) | ((unsigned)f2bs(b.y) << 16);
    o.w = (unsigned)f2bs(b.z) | ((unsigned)f2bs(b.w) << 16);
    ((uint4*)(xg + (long)row * 2048))[threadIdx.x] = o;
}

// ---------------- transpose+cast weights: Wt[n][k] = bf16(W[k][n]) ----------------
__global__ void k_transpose(const float* __restrict__ W, unsigned short* __restrict__ Wt,
                            int K, int N, int Npad) {
    __shared__ float tile[32][33];
    const int n0 = blockIdx.x * 32, k0 = blockIdx.y * 32;
    const int tx = threadIdx.x, ty = threadIdx.y;   // 32 x 8
    #pragma unroll
    for (int i = 0; i < 32; i += 8) {
        int n = n0 + tx, k = k0 + ty + i;
        tile[ty + i][tx] = (n < N) ? W[(long)k * N + n] : 0.f;
    }
    __syncthreads();
    #pragma unroll
    for (int i = 0; i < 32; i += 8) {
        int n = n0 + ty + i, k = k0 + tx;
        if (n < Npad) Wt[(long)n * K + k] = f2bs(tile[tx][ty + i]);
    }
}

// ---------------- bf16 GEMM: C[M,N] = A[M,K] @ Bt[N,K]^T + bias ----------------
// 128x128 tile, BK=64, 4 waves (2x2), 16x16x32 MFMA, global_load_lds staging with
// pre-swizzled source (slot ^= row&7) + matching XOR-swizzled ds_read (2-way max).
template <int RELU, int F32OUT>
__global__ __launch_bounds__(256) void k_gemm(const unsigned short* __restrict__ A,
                                              const unsigned short* __restrict__ Bt,
                                              const float* __restrict__ bias,
                                              unsigned short* __restrict__ Cb,
                                              float* __restrict__ Cf,
                                              int M, int N, int K, int ldc) {
    constexpr int BK = 64;
    __shared__ unsigned short As[128 * BK];
    __shared__ unsigned short Bs[128 * BK];
    const int tid  = threadIdx.x;
    const int lane = tid & 63;
    const int wv   = tid >> 6;
    const int brow = blockIdx.x * 128;
    const int bcol = blockIdx.y * 128;
    const int wr   = (wv >> 1) * 64;
    const int wc   = (wv & 1) * 64;
    const int frow = lane & 15;
    const int kg   = lane >> 4;
    const int rx   = frow & 7;
    const int srow  = lane >> 3;                 // 0..7 row within 8-row chunk
    const int sslot = (lane & 7) ^ srow;         // pre-swizzled 16B slot in source row

    f32x4 acc[4][4];
    #pragma unroll
    for (int m = 0; m < 4; m++)
        #pragma unroll
        for (int n = 0; n < 4; n++)
            #pragma unroll
            for (int r = 0; r < 4; r++) acc[m][n][r] = 0.f;

    for (int kt = 0; kt < K; kt += BK) {
        #pragma unroll
        for (int i = 0; i < 4; i++) {
            const int c = wv * 4 + i;
            const int r = c * 8 + srow;
            GLD16(A + (long)(brow + r) * K + kt + sslot * 8, &As[c * 512]);
        }
        #pragma unroll
        for (int i = 0; i < 4; i++) {
            const int c = wv * 4 + i;
            const int r = c * 8 + srow;
            GLD16(Bt + (long)(bcol + r) * K + kt + sslot * 8, &Bs[c * 512]);
        }
        __syncthreads();
        #pragma unroll
        for (int kk = 0; kk < 2; kk++) {
            bf16x8 av[4], bv[4];
            #pragma unroll
            for (int m = 0; m < 4; m++) {
                const int row = wr + m * 16 + frow;
                av[m] = *(const bf16x8*)&As[row * BK + (((kk * 4 + kg) ^ rx) * 8)];
            }
            #pragma unroll
            for (int n = 0; n < 4; n++) {
                const int row = wc + n * 16 + frow;
                bv[n] = *(const bf16x8*)&Bs[row * BK + (((kk * 4 + kg) ^ rx) * 8)];
            }
            #pragma unroll
            for (int m = 0; m < 4; m++)
                #pragma unroll
                for (int n = 0; n < 4; n++)
                    acc[m][n] = __builtin_amdgcn_mfma_f32_16x16x32_bf16(av[m], bv[n],
                                                                        acc[m][n], 0, 0, 0);
        }
        __syncthreads();
    }
    const int r0 = brow + wr + (lane >> 4) * 4;
    const int c0 = bcol + wc + (lane & 15);
    #pragma unroll
    for (int n = 0; n < 4; n++) {
        const int col = c0 + n * 16;
        if (col < N) {
            const float bb = bias[col];
            #pragma unroll
            for (int m = 0; m < 4; m++) {
                #pragma unroll
                for (int r = 0; r < 4; r++) {
                    const int row = r0 + m * 16 + r;
                    float v = acc[m][n][r] + bb;
                    if (RELU) v = fmaxf(v, 0.f);
                    if (F32OUT) Cf[(long)row * ldc + col] = v;
                    else        Cb[(long)row * ldc + col] = f2bs(v);
                }
            }
        }
    }
}

// ---------------- BatchNorm: column sums / finalize / apply ----------------
__global__ void k_bnstats(const unsigned short* __restrict__ t, float* __restrict__ sums,
                          int ncols) {
    const int col = blockIdx.x * blockDim.x + threadIdx.x;
    const int r0  = blockIdx.y * 256;
    float s = 0.f, sq = 0.f;
    for (int r = 0; r < 256; r++) {
        float v = bs2f(t[(long)(r0 + r) * ncols + col]);
        s += v; sq += v * v;
    }
    atomicAdd(&sums[col], s);
    atomicAdd(&sums[ncols + col], sq);
}

__global__ void k_bnfin(float* __restrict__ sums, const float* __restrict__ g,
                        const float* __restrict__ be, int ncols) {
    const int c = blockIdx.x * blockDim.x + threadIdx.x;
    const float m   = sums[c] * (1.f / NB);
    const float var = sums[ncols + c] * (1.f / NB) - m * m;
    const float sc  = rsqrtf(var + EPSV) * g[c];
    sums[c] = sc;
    sums[ncols + c] = be[c] - m * sc;
}

template <int RELU>
__global__ void k_bnapply(unsigned short* __restrict__ t, const float* __restrict__ sums,
                          int ncols) {
    const long i  = ((long)blockIdx.x * blockDim.x + threadIdx.x) * 8;
    const int  c0 = (int)(i & (ncols - 1));
    uint4 v = *(uint4*)(t + i);
    unsigned int us[8] = {v.x & 0xffffu, v.x >> 16, v.y & 0xffffu, v.y >> 16,
                          v.z & 0xffffu, v.z >> 16, v.w & 0xffffu, v.w >> 16};
    unsigned int po[8];
    #pragma unroll
    for (int j = 0; j < 8; j++) {
        const int c = c0 + j;
        float val = bs2f(us[j]) * sums[c] + sums[ncols + c];
        if (RELU) val = fmaxf(val, 0.f);
        po[j] = f2bs(val);
    }
    uint4 o;
    o.x = po[0] | (po[1] << 16); o.y = po[2] | (po[3] << 16);
    o.z = po[4] | (po[5] << 16); o.w = po[6] | (po[7] << 16);
    *(uint4*)(t + i) = o;
}

// ---------------- logit losses: CE + mse(out,out2) + mse(out,mix) ----------------
__global__ void k_logitloss(const float* __restrict__ out, const int* __restrict__ y,
                            const int* __restrict__ order, const int* __restrict__ s1,
                            const int* __restrict__ s2, const float* __restrict__ lamp,
                            float* __restrict__ acc) {
    const int i = blockIdx.x;
    const int lane = threadIdx.x;   // 64
    const float lam = lamp[0];
    const float* o  = out + (long)i * NCP;
    const float* o2 = out + (long)s1[i] * NCP;
    const float* o3 = out + (long)s2[i] * NCP;
    float v[6];
    float mx = -1e30f, d1 = 0.f, d2 = 0.f;
    #pragma unroll
    for (int j = 0; j < 6; j++) {
        const int c = lane + j * 64;
        if (c < NC) {
            const float a = o[c], b = o2[c], cc = o3[c];
            const float mix = lam * b + (1.f - lam) * cc;
            v[j] = a;
            d1 += (a - b) * (a - b);
            d2 += (a - mix) * (a - mix);
            mx = fmaxf(mx, a);
        } else v[j] = -1e30f;
    }
    #pragma unroll
    for (int off = 32; off; off >>= 1) mx = fmaxf(mx, __shfl_xor(mx, off));
    float se = 0.f;
    #pragma unroll
    for (int j = 0; j < 6; j++) {
        const int c = lane + j * 64;
        if (c < NC) se += expf(v[j] - mx);
    }
    #pragma unroll
    for (int off = 32; off; off >>= 1) {
        se += __shfl_xor(se, off);
        d1 += __shfl_xor(d1, off);
        d2 += __shfl_xor(d2, off);
    }
    if (lane == 0) {
        const int yv = y[order[i]];
        const float logp = o[yv] - mx - logf(se);
        atomicAdd(&acc[0], -logp);
        atomicAdd(&acc[1], d1);
        atomicAdd(&acc[2], d2);
    }
}

// ---------------- proj feature losses ----------------
__global__ void k_featloss(const unsigned short* __restrict__ proj, const int* __restrict__ s1,
                           const int* __restrict__ s2, const float* __restrict__ lamp,
                           float* __restrict__ acc) {
    const int i = blockIdx.x;
    const int t = threadIdx.x;   // 256, one uint4 (8 bf16) each
    const float lam = lamp[0];
    uint4 a = ((const uint4*)(proj + (long)i * NF))[t];
    uint4 b = ((const uint4*)(proj + (long)s1[i] * NF))[t];
    uint4 c = ((const uint4*)(proj + (long)s2[i] * NF))[t];
    unsigned int ua[8] = {a.x & 0xffffu, a.x >> 16, a.y & 0xffffu, a.y >> 16,
                          a.z & 0xffffu, a.z >> 16, a.w & 0xffffu, a.w >> 16};
    unsigned int ub[8] = {b.x & 0xffffu, b.x >> 16, b.y & 0xffffu, b.y >> 16,
                          b.z & 0xffffu, b.z >> 16, b.w & 0xffffu, b.w >> 16};
    unsigned int uc[8] = {c.x & 0xffffu, c.x >> 16, c.y & 0xffffu, c.y >> 16,
                          c.z & 0xffffu, c.z >> 16, c.w & 0xffffu, c.w >> 16};
    float d1 = 0.f, d2 = 0.f;
    #pragma unroll
    for (int j = 0; j < 8; j++) {
        float pa = bs2f(ua[j]), pb = bs2f(ub[j]), pc = bs2f(uc[j]);
        float mix = lam * pb + (1.f - lam) * pc;
        d1 += (pa - pb) * (pa - pb);
        d2 += (pa - mix) * (pa - mix);
    }
    #pragma unroll
    for (int off = 32; off; off >>= 1) {
        d1 += __shfl_xor(d1, off);
        d2 += __shfl_xor(d2, off);
    }
    __shared__ float r1[4], r2[4];
    if ((t & 63) == 0) { r1[t >> 6] = d1; r2[t >> 6] = d2; }
    __syncthreads();
    if (t == 0) {
        atomicAdd(&acc[3], r1[0] + r1[1] + r1[2] + r1[3]);
        atomicAdd(&acc[4], r2[0] + r2[1] + r2[2] + r2[3]);
    }
}

__global__ void k_final(const float* __restrict__ acc, const float* __restrict__ lamp,
                        float* __restrict__ outp) {
    const float lam = lamp[0];
    const float cl  = acc[0] * (1.f / NB);
    const float Lil = acc[1] * (1.f / ((float)NB * NC));
    const float Lhl = acc[2] * (1.f / ((float)NB * NC));
    const float Lif = 0.3f * acc[3] * (1.f / ((float)NB * NF));
    const float Lhf = 0.3f * acc[4] * (1.f / ((float)NB * NF));
    const float Cs  = fminf(cl, 1.f);
    outp[0] = cl + Cs * (lam * (Lil + Lif) + (1.f - lam) * (Lhl + Lhf));
}

extern "C" void kernel_launch(void* const* d_in, const int* in_sizes, int n_in,
                              void* d_out, int out_size, void* d_ws, size_t ws_size,
                              hipStream_t stream) {
    const float* x   = (const float*)d_in[0];
    const float* lam = (const float*)d_in[1];
    const float* Wf  = (const float*)d_in[2];
    const float* bf_ = (const float*)d_in[3];
    const float* W1  = (const float*)d_in[4];
    const float* b1  = (const float*)d_in[5];
    const float* g1  = (const float*)d_in[6];
    const float* be1 = (const float*)d_in[7];
    const float* W2  = (const float*)d_in[8];
    const float* b2  = (const float*)d_in[9];
    const float* g2  = (const float*)d_in[10];
    const float* be2 = (const float*)d_in[11];
    const float* W3  = (const float*)d_in[12];
    const float* b3  = (const float*)d_in[13];
    const float* g3  = (const float*)d_in[14];
    const float* be3 = (const float*)d_in[15];
    const float* Wc  = (const float*)d_in[16];
    const float* bc  = (const float*)d_in[17];
    const int* y     = (const int*)d_in[18];
    const int* order = (const int*)d_in[19];
    const int* s1    = (const int*)d_in[20];
    const int* s2    = (const int*)d_in[21];
    float* outp = (float*)d_out;

    char* ws = (char*)d_ws;
    const size_t SZ_ACT = (size_t)NB * 2048 * 2;                    // 32 MiB
    unsigned short* bufA = (unsigned short*)(ws);                   // xg -> t2/h2
    unsigned short* bufB = (unsigned short*)(ws + SZ_ACT);          // feat -> t3/proj
    unsigned short* bufC = (unsigned short*)(ws + 2 * SZ_ACT);      // t1/h1
    float* outbuf = (float*)(ws + 3 * SZ_ACT);                      // 8192 x 384 f32
    size_t off = 3 * SZ_ACT + (size_t)NB * NCP * 4;
    unsigned short* WT0 = (unsigned short*)(ws + off); off += (size_t)2048 * 2048 * 2;
    unsigned short* WT1 = (unsigned short*)(ws + off); off += (size_t)2048 * 2048 * 2;
    unsigned short* WT2 = (unsigned short*)(ws + off); off += (size_t)2048 * 2048 * 2;
    unsigned short* WT3 = (unsigned short*)(ws + off); off += (size_t)2048 * 2048 * 2;
    unsigned short* WCT = (unsigned short*)(ws + off); off += (size_t)NCP * 2048 * 2;
    float* stats = (float*)(ws + off);                               // 3 x 4096 floats
    float* accs  = stats + 3 * 4096;                                 // 5 floats used

    hipMemsetAsync(stats, 0, (3 * 4096 + 8) * sizeof(float), stream);

    dim3 tb(32, 8);
    k_transpose<<<dim3(64, 64), tb, 0, stream>>>(Wf, WT0, 2048, 2048, 2048);
    k_transpose<<<dim3(64, 64), tb, 0, stream>>>(W1, WT1, 2048, 2048, 2048);
    k_transpose<<<dim3(64, 64), tb, 0, stream>>>(W2, WT2, 2048, 2048, 2048);
    k_transpose<<<dim3(64, 64), tb, 0, stream>>>(W3, WT3, 2048, 2048, 2048);
    k_transpose<<<dim3(12, 64), tb, 0, stream>>>(Wc, WCT, 2048, NC, NCP);

    k_gather<<<NB, 256, 0, stream>>>(x, order, bufA);

    // feat = relu(xg @ Wf + bf)
    k_gemm<1, 0><<<dim3(64, 16), 256, 0, stream>>>(bufA, WT0, bf_, bufB, nullptr, NB, 2048, 2048, 2048);
    // out = feat @ Wc + bc   (f32, ldc=384)
    k_gemm<0, 1><<<dim3(64, 3), 256, 0, stream>>>(bufB, WCT, bc, nullptr, outbuf, NB, NC, 2048, NCP);
    // t1 = feat @ W1 + b1 ; h1 = relu(bn(t1))
    k_gemm<0, 0><<<dim3(64, 16), 256, 0, stream>>>(bufB, WT1, b1, bufC, nullptr, NB, 2048, 2048, 2048);
    k_bnstats<<<dim3(8, 32), 256, 0, stream>>>(bufC, stats, 2048);
    k_bnfin<<<8, 256, 0, stream>>>(stats, g1, be1, 2048);
    k_bnapply<1><<<8192, 256, 0, stream>>>(bufC, stats, 2048);
    // t2 = h1 @ W2 + b2 ; h2 = relu(bn(t2))
    k_gemm<0, 0><<<dim3(64, 16), 256, 0, stream>>>(bufC, WT2, b2, bufA, nullptr, NB, 2048, 2048, 2048);
    k_bnstats<<<dim3(8, 32), 256, 0, stream>>>(bufA, stats + 4096, 2048);
    k_bnfin<<<8, 256, 0, stream>>>(stats + 4096, g2, be2, 2048);
    k_bnapply<1><<<8192, 256, 0, stream>>>(bufA, stats + 4096, 2048);
    // t3 = h2 @ W3 + b3 ; proj = bn(t3)
    k_gemm<0, 0><<<dim3(64, 16), 256, 0, stream>>>(bufA, WT3, b3, bufB, nullptr, NB, 2048, 2048, 2048);
    k_bnstats<<<dim3(8, 32), 256, 0, stream>>>(bufB, stats + 8192, 2048);
    k_bnfin<<<8, 256, 0, stream>>>(stats + 8192, g3, be3, 2048);
    k_bnapply<0><<<8192, 256, 0, stream>>>(bufB, stats + 8192, 2048);

    k_logitloss<<<NB, 64, 0, stream>>>(outbuf, y, order, s1, s2, lam, accs);
    k_featloss<<<NB, 256, 0, stream>>>(bufB, s1, s2, lam, accs);
    k_final<<<1, 1, 0, stream>>>(accs, lam, outp);
}

// Round 2
// 578.373 us; speedup vs baseline: 1.8240x; 1.8240x over previous
//
#include <hip/hip_runtime.h>

#define NB   8192
#define NF   2048
#define NC   345
#define NCP  384
#define EPSV 1e-5f

typedef __bf16 bf16x8 __attribute__((ext_vector_type(8)));
typedef float  f32x4  __attribute__((ext_vector_type(4)));

__device__ __forceinline__ float bs2f(unsigned int u) { return __uint_as_float(u << 16); }
__device__ __forceinline__ unsigned short f2bs(float f) {
    unsigned int u = __float_as_uint(f);
    u += 0x7fffu + ((u >> 16) & 1u);   // round-to-nearest-even
    return (unsigned short)(u >> 16);
}

#define GLD16(g, l)                                                                     \
    __builtin_amdgcn_global_load_lds((const __attribute__((address_space(1))) void*)(g),\
                                     (__attribute__((address_space(3))) void*)(l),      \
                                     16, 0, 0)

// ---------------- gather + cast x rows: xg[i] = bf16(x[order[i]]) ----------------
__global__ void k_gather(const float* __restrict__ x, const int* __restrict__ order,
                         unsigned short* __restrict__ xg) {
    const int row = blockIdx.x;
    const long src = order[row];
    const float4* xr = (const float4*)(x + src * 2048);
    float4 a = xr[threadIdx.x * 2 + 0];
    float4 b = xr[threadIdx.x * 2 + 1];
    uint4 o;
    o.x = (unsigned)f2bs(a.x) | ((unsigned)f2bs(a.y) << 16);
    o.y = (unsigned)f2bs(a.z) | ((unsigned)f2bs(a.w) << 16);
    o.z = (unsigned)f2bs(b.x) | ((unsigned)f2bs(b.y) << 16);
    o.w = (unsigned)f2bs(b.z) | ((unsigned)f2bs(b.w) << 16);
    ((uint4*)(xg + (long)row * 2048))[threadIdx.x] = o;
}

// ---------------- transpose+cast weights: Wt[n][k] = bf16(W[k][n]) ----------------
__global__ void k_transpose(const float* __restrict__ W, unsigned short* __restrict__ Wt,
                            int K, int N, int Npad) {
    __shared__ float tile[32][33];
    const int n0 = blockIdx.x * 32, k0 = blockIdx.y * 32;
    const int tx = threadIdx.x, ty = threadIdx.y;   // 32 x 8
    #pragma unroll
    for (int i = 0; i < 32; i += 8) {
        int n = n0 + tx, k = k0 + ty + i;
        tile[ty + i][tx] = (n < N) ? W[(long)k * N + n] : 0.f;
    }
    __syncthreads();
    #pragma unroll
    for (int i = 0; i < 32; i += 8) {
        int n = n0 + ty + i, k = k0 + tx;
        if (n < Npad) Wt[(long)n * K + k] = f2bs(tile[tx][ty + i]);
    }
}

// ---------------- bf16 GEMM: C[M,N] = A[M,K] @ Bt[N,K]^T + bias ----------------
// 128x128 tile, BK=64, 4 waves (2x2), 16x16x32 MFMA, global_load_lds staging with
// pre-swizzled source (slot ^= row&7) + matching XOR-swizzled ds_read (2-way max).
template <int RELU, int F32OUT>
__global__ __launch_bounds__(256) void k_gemm(const unsigned short* __restrict__ A,
                                              const unsigned short* __restrict__ Bt,
                                              const float* __restrict__ bias,
                                              unsigned short* __restrict__ Cb,
                                              float* __restrict__ Cf,
                                              int M, int N, int K, int ldc) {
    constexpr int BK = 64;
    __shared__ unsigned short As[128 * BK];
    __shared__ unsigned short Bs[128 * BK];
    const int tid  = threadIdx.x;
    const int lane = tid & 63;
    const int wv   = tid >> 6;
    const int brow = blockIdx.x * 128;
    const int bcol = blockIdx.y * 128;
    const int wr   = (wv >> 1) * 64;
    const int wc   = (wv & 1) * 64;
    const int frow = lane & 15;
    const int kg   = lane >> 4;
    const int rx   = frow & 7;
    const int srow  = lane >> 3;                 // 0..7 row within 8-row chunk
    const int sslot = (lane & 7) ^ srow;         // pre-swizzled 16B slot in source row

    f32x4 acc[4][4];
    #pragma unroll
    for (int m = 0; m < 4; m++)
        #pragma unroll
        for (int n = 0; n < 4; n++)
            #pragma unroll
            for (int r = 0; r < 4; r++) acc[m][n][r] = 0.f;

    for (int kt = 0; kt < K; kt += BK) {
        #pragma unroll
        for (int i = 0; i < 4; i++) {
            const int c = wv * 4 + i;
            const int r = c * 8 + srow;
            GLD16(A + (long)(brow + r) * K + kt + sslot * 8, &As[c * 512]);
        }
        #pragma unroll
        for (int i = 0; i < 4; i++) {
            const int c = wv * 4 + i;
            const int r = c * 8 + srow;
            GLD16(Bt + (long)(bcol + r) * K + kt + sslot * 8, &Bs[c * 512]);
        }
        __syncthreads();
        #pragma unroll
        for (int kk = 0; kk < 2; kk++) {
            bf16x8 av[4], bv[4];
            #pragma unroll
            for (int m = 0; m < 4; m++) {
                const int row = wr + m * 16 + frow;
                av[m] = *(const bf16x8*)&As[row * BK + (((kk * 4 + kg) ^ rx) * 8)];
            }
            #pragma unroll
            for (int n = 0; n < 4; n++) {
                const int row = wc + n * 16 + frow;
                bv[n] = *(const bf16x8*)&Bs[row * BK + (((kk * 4 + kg) ^ rx) * 8)];
            }
            #pragma unroll
            for (int m = 0; m < 4; m++)
                #pragma unroll
                for (int n = 0; n < 4; n++)
                    acc[m][n] = __builtin_amdgcn_mfma_f32_16x16x32_bf16(av[m], bv[n],
                                                                        acc[m][n], 0, 0, 0);
        }
        __syncthreads();
    }
    const int r0 = brow + wr + (lane >> 4) * 4;
    const int c0 = bcol + wc + (lane & 15);
    #pragma unroll
    for (int n = 0; n < 4; n++) {
        const int col = c0 + n * 16;
        if (col < N) {
            const float bb = bias[col];
            #pragma unroll
            for (int m = 0; m < 4; m++) {
                #pragma unroll
                for (int r = 0; r < 4; r++) {
                    const int row = r0 + m * 16 + r;
                    float v = acc[m][n][r] + bb;
                    if (RELU) v = fmaxf(v, 0.f);
                    if (F32OUT) Cf[(long)row * ldc + col] = v;
                    else        Cb[(long)row * ldc + col] = f2bs(v);
                }
            }
        }
    }
}

// ---------------- BatchNorm: column sums / finalize / apply ----------------
__global__ void k_bnstats(const unsigned short* __restrict__ t, float* __restrict__ sums,
                          int ncols) {
    const int col = blockIdx.x * blockDim.x + threadIdx.x;
    const int r0  = blockIdx.y * 256;
    float s = 0.f, sq = 0.f;
    for (int r = 0; r < 256; r++) {
        float v = bs2f(t[(long)(r0 + r) * ncols + col]);
        s += v; sq += v * v;
    }
    atomicAdd(&sums[col], s);
    atomicAdd(&sums[ncols + col], sq);
}

__global__ void k_bnfin(float* __restrict__ sums, const float* __restrict__ g,
                        const float* __restrict__ be, int ncols) {
    const int c = blockIdx.x * blockDim.x + threadIdx.x;
    const float m   = sums[c] * (1.f / NB);
    const float var = sums[ncols + c] * (1.f / NB) - m * m;
    const float sc  = rsqrtf(var + EPSV) * g[c];
    sums[c] = sc;
    sums[ncols + c] = be[c] - m * sc;
}

template <int RELU>
__global__ void k_bnapply(unsigned short* __restrict__ t, const float* __restrict__ sums,
                          int ncols) {
    const long i  = ((long)blockIdx.x * blockDim.x + threadIdx.x) * 8;
    const int  c0 = (int)(i & (ncols - 1));
    uint4 v = *(uint4*)(t + i);
    unsigned int us[8] = {v.x & 0xffffu, v.x >> 16, v.y & 0xffffu, v.y >> 16,
                          v.z & 0xffffu, v.z >> 16, v.w & 0xffffu, v.w >> 16};
    unsigned int po[8];
    #pragma unroll
    for (int j = 0; j < 8; j++) {
        const int c = c0 + j;
        float val = bs2f(us[j]) * sums[c] + sums[ncols + c];
        if (RELU) val = fmaxf(val, 0.f);
        po[j] = f2bs(val);
    }
    uint4 o;
    o.x = po[0] | (po[1] << 16); o.y = po[2] | (po[3] << 16);
    o.z = po[4] | (po[5] << 16); o.w = po[6] | (po[7] << 16);
    *(uint4*)(t + i) = o;
}

// ---------------- logit losses: CE + mse(out,out2) + mse(out,mix) ----------------
// Grid-stride over rows, per-lane accumulation, ONE atomic triple per block.
__global__ __launch_bounds__(256) void k_logitloss(const float* __restrict__ out,
                            const int* __restrict__ y,
                            const int* __restrict__ order, const int* __restrict__ s1,
                            const int* __restrict__ s2, const float* __restrict__ lamp,
                            float* __restrict__ acc) {
    const int lane = threadIdx.x & 63;
    const int wv   = threadIdx.x >> 6;
    const int wid  = blockIdx.x * 4 + wv;
    const int nw   = gridDim.x * 4;
    const float lam = lamp[0];
    float ce = 0.f, d1 = 0.f, d2 = 0.f;
    for (int i = wid; i < NB; i += nw) {
        const float* o  = out + (long)i * NCP;
        const float* o2 = out + (long)s1[i] * NCP;
        const float* o3 = out + (long)s2[i] * NCP;
        float v[6];
        float mx = -1e30f;
        #pragma unroll
        for (int j = 0; j < 6; j++) {
            const int c = lane + j * 64;
            if (c < NC) {
                const float a = o[c], b = o2[c], cc = o3[c];
                const float mix = lam * b + (1.f - lam) * cc;
                v[j] = a;
                d1 += (a - b) * (a - b);
                d2 += (a - mix) * (a - mix);
                mx = fmaxf(mx, a);
            } else v[j] = -1e30f;
        }
        #pragma unroll
        for (int off = 32; off; off >>= 1) mx = fmaxf(mx, __shfl_xor(mx, off));
        float se = 0.f;
        #pragma unroll
        for (int j = 0; j < 6; j++) se += expf(v[j] - mx);   // pad lanes underflow to 0
        #pragma unroll
        for (int off = 32; off; off >>= 1) se += __shfl_xor(se, off);
        if (lane == 0) {
            const int yv = y[order[i]];
            ce += mx + logf(se) - o[yv];
        }
    }
    #pragma unroll
    for (int off = 32; off; off >>= 1) {
        d1 += __shfl_xor(d1, off);
        d2 += __shfl_xor(d2, off);
    }
    __shared__ float red[4][3];
    if (lane == 0) { red[wv][0] = ce; red[wv][1] = d1; red[wv][2] = d2; }
    __syncthreads();
    if (threadIdx.x == 0) {
        atomicAdd(&acc[0], red[0][0] + red[1][0] + red[2][0] + red[3][0]);
        atomicAdd(&acc[1], red[0][1] + red[1][1] + red[2][1] + red[3][1]);
        atomicAdd(&acc[2], red[0][2] + red[1][2] + red[2][2] + red[3][2]);
    }
}

// ---------------- proj feature losses ----------------
// Grid-stride over rows, per-thread accumulation, ONE atomic pair per block.
__global__ __launch_bounds__(256) void k_featloss(const unsigned short* __restrict__ proj,
                           const int* __restrict__ s1,
                           const int* __restrict__ s2, const float* __restrict__ lamp,
                           float* __restrict__ acc) {
    const int t = threadIdx.x;   // 256, one uint4 (8 bf16) each per row
    const float lam = lamp[0];
    float d1 = 0.f, d2 = 0.f;
    for (int i = blockIdx.x; i < NB; i += gridDim.x) {
        uint4 a = ((const uint4*)(proj + (long)i * NF))[t];
        uint4 b = ((const uint4*)(proj + (long)s1[i] * NF))[t];
        uint4 c = ((const uint4*)(proj + (long)s2[i] * NF))[t];
        unsigned int ua[8] = {a.x & 0xffffu, a.x >> 16, a.y & 0xffffu, a.y >> 16,
                              a.z & 0xffffu, a.z >> 16, a.w & 0xffffu, a.w >> 16};
        unsigned int ub[8] = {b.x & 0xffffu, b.x >> 16, b.y & 0xffffu, b.y >> 16,
                              b.z & 0xffffu, b.z >> 16, b.w & 0xffffu, b.w >> 16};
        unsigned int uc[8] = {c.x & 0xffffu, c.x >> 16, c.y & 0xffffu, c.y >> 16,
                              c.z & 0xffffu, c.z >> 16, c.w & 0xffffu, c.w >> 16};
        #pragma unroll
        for (int j = 0; j < 8; j++) {
            float pa = bs2f(ua[j]), pb = bs2f(ub[j]), pc = bs2f(uc[j]);
            float mix = lam * pb + (1.f - lam) * pc;
            d1 += (pa - pb) * (pa - pb);
            d2 += (pa - mix) * (pa - mix);
        }
    }
    #pragma unroll
    for (int off = 32; off; off >>= 1) {
        d1 += __shfl_xor(d1, off);
        d2 += __shfl_xor(d2, off);
    }
    __shared__ float r1[4], r2[4];
    if ((t & 63) == 0) { r1[t >> 6] = d1; r2[t >> 6] = d2; }
    __syncthreads();
    if (t == 0) {
        atomicAdd(&acc[3], r1[0] + r1[1] + r1[2] + r1[3]);
        atomicAdd(&acc[4], r2[0] + r2[1] + r2[2] + r2[3]);
    }
}

__global__ void k_final(const float* __restrict__ acc, const float* __restrict__ lamp,
                        float* __restrict__ outp) {
    const float lam = lamp[0];
    const float cl  = acc[0] * (1.f / NB);
    const float Lil = acc[1] * (1.f / ((float)NB * NC));
    const float Lhl = acc[2] * (1.f / ((float)NB * NC));
    const float Lif = 0.3f * acc[3] * (1.f / ((float)NB * NF));
    const float Lhf = 0.3f * acc[4] * (1.f / ((float)NB * NF));
    const float Cs  = fminf(cl, 1.f);
    outp[0] = cl + Cs * (lam * (Lil + Lif) + (1.f - lam) * (Lhl + Lhf));
}

extern "C" void kernel_launch(void* const* d_in, const int* in_sizes, int n_in,
                              void* d_out, int out_size, void* d_ws, size_t ws_size,
                              hipStream_t stream) {
    const float* x   = (const float*)d_in[0];
    const float* lam = (const float*)d_in[1];
    const float* Wf  = (const float*)d_in[2];
    const float* bf_ = (const float*)d_in[3];
    const float* W1  = (const float*)d_in[4];
    const float* b1  = (const float*)d_in[5];
    const float* g1  = (const float*)d_in[6];
    const float* be1 = (const float*)d_in[7];
    const float* W2  = (const float*)d_in[8];
    const float* b2  = (const float*)d_in[9];
    const float* g2  = (const float*)d_in[10];
    const float* be2 = (const float*)d_in[11];
    const float* W3  = (const float*)d_in[12];
    const float* b3  = (const float*)d_in[13];
    const float* g3  = (const float*)d_in[14];
    const float* be3 = (const float*)d_in[15];
    const float* Wc  = (const float*)d_in[16];
    const float* bc  = (const float*)d_in[17];
    const int* y     = (const int*)d_in[18];
    const int* order = (const int*)d_in[19];
    const int* s1    = (const int*)d_in[20];
    const int* s2    = (const int*)d_in[21];
    float* outp = (float*)d_out;

    char* ws = (char*)d_ws;
    const size_t SZ_ACT = (size_t)NB * 2048 * 2;                    // 32 MiB
    unsigned short* bufA = (unsigned short*)(ws);                   // xg -> t2/h2
    unsigned short* bufB = (unsigned short*)(ws + SZ_ACT);          // feat -> t3/proj
    unsigned short* bufC = (unsigned short*)(ws + 2 * SZ_ACT);      // t1/h1
    float* outbuf = (float*)(ws + 3 * SZ_ACT);                      // 8192 x 384 f32
    size_t off = 3 * SZ_ACT + (size_t)NB * NCP * 4;
    unsigned short* WT0 = (unsigned short*)(ws + off); off += (size_t)2048 * 2048 * 2;
    unsigned short* WT1 = (unsigned short*)(ws + off); off += (size_t)2048 * 2048 * 2;
    unsigned short* WT2 = (unsigned short*)(ws + off); off += (size_t)2048 * 2048 * 2;
    unsigned short* WT3 = (unsigned short*)(ws + off); off += (size_t)2048 * 2048 * 2;
    unsigned short* WCT = (unsigned short*)(ws + off); off += (size_t)NCP * 2048 * 2;
    float* stats = (float*)(ws + off);                               // 3 x 4096 floats
    float* accs  = stats + 3 * 4096;                                 // 5 floats used

    hipMemsetAsync(stats, 0, (3 * 4096 + 8) * sizeof(float), stream);

    dim3 tb(32, 8);
    k_transpose<<<dim3(64, 64), tb, 0, stream>>>(Wf, WT0, 2048, 2048, 2048);
    k_transpose<<<dim3(64, 64), tb, 0, stream>>>(W1, WT1, 2048, 2048, 2048);
    k_transpose<<<dim3(64, 64), tb, 0, stream>>>(W2, WT2, 2048, 2048, 2048);
    k_transpose<<<dim3(64, 64), tb, 0, stream>>>(W3, WT3, 2048, 2048, 2048);
    k_transpose<<<dim3(12, 64), tb, 0, stream>>>(Wc, WCT, 2048, NC, NCP);

    k_gather<<<NB, 256, 0, stream>>>(x, order, bufA);

    // feat = relu(xg @ Wf + bf)
    k_gemm<1, 0><<<dim3(64, 16), 256, 0, stream>>>(bufA, WT0, bf_, bufB, nullptr, NB, 2048, 2048, 2048);
    // out = feat @ Wc + bc   (f32, ldc=384)
    k_gemm<0, 1><<<dim3(64, 3), 256, 0, stream>>>(bufB, WCT, bc, nullptr, outbuf, NB, NC, 2048, NCP);
    // t1 = feat @ W1 + b1 ; h1 = relu(bn(t1))
    k_gemm<0, 0><<<dim3(64, 16), 256, 0, stream>>>(bufB, WT1, b1, bufC, nullptr, NB, 2048, 2048, 2048);
    k_bnstats<<<dim3(8, 32), 256, 0, stream>>>(bufC, stats, 2048);
    k_bnfin<<<8, 256, 0, stream>>>(stats, g1, be1, 2048);
    k_bnapply<1><<<8192, 256, 0, stream>>>(bufC, stats, 2048);
    // t2 = h1 @ W2 + b2 ; h2 = relu(bn(t2))
    k_gemm<0, 0><<<dim3(64, 16), 256, 0, stream>>>(bufC, WT2, b2, bufA, nullptr, NB, 2048, 2048, 2048);
    k_bnstats<<<dim3(8, 32), 256, 0, stream>>>(bufA, stats + 4096, 2048);
    k_bnfin<<<8, 256, 0, stream>>>(stats + 4096, g2, be2, 2048);
    k_bnapply<1><<<8192, 256, 0, stream>>>(bufA, stats + 4096, 2048);
    // t3 = h2 @ W3 + b3 ; proj = bn(t3)
    k_gemm<0, 0><<<dim3(64, 16), 256, 0, stream>>>(bufA, WT3, b3, bufB, nullptr, NB, 2048, 2048, 2048);
    k_bnstats<<<dim3(8, 32), 256, 0, stream>>>(bufB, stats + 8192, 2048);
    k_bnfin<<<8, 256, 0, stream>>>(stats + 8192, g3, be3, 2048);
    k_bnapply<0><<<8192, 256, 0, stream>>>(bufB, stats + 8192, 2048);

    k_logitloss<<<256, 256, 0, stream>>>(outbuf, y, order, s1, s2, lam, accs);
    k_featloss<<<512, 256, 0, stream>>>(bufB, s1, s2, lam, accs);
    k_final<<<1, 1, 0, stream>>>(accs, lam, outp);
}

// Round 3
// 449.291 us; speedup vs baseline: 2.3480x; 1.2873x over previous
//
#include <hip/hip_runtime.h>

#define NB   8192
#define NF   2048
#define NC   345
#define NCP  384
#define EPSV 1e-5f

typedef __bf16 bf16x8 __attribute__((ext_vector_type(8)));
typedef float  f32x4  __attribute__((ext_vector_type(4)));

__device__ __forceinline__ float bs2f(unsigned int u) { return __uint_as_float(u << 16); }
__device__ __forceinline__ unsigned short f2bs(float f) {
    unsigned int u = __float_as_uint(f);
    u += 0x7fffu + ((u >> 16) & 1u);   // round-to-nearest-even
    return (unsigned short)(u >> 16);
}

#define GLD16(g, l)                                                                     \
    __builtin_amdgcn_global_load_lds((const __attribute__((address_space(1))) void*)(g),\
                                     (__attribute__((address_space(3))) void*)(l),      \
                                     16, 0, 0)

// ---------------- gather + cast x rows: xg[i] = bf16(x[order[i]]) ----------------
__global__ void k_gather(const float* __restrict__ x, const int* __restrict__ order,
                         unsigned short* __restrict__ xg) {
    const int row = blockIdx.x;
    const long src = order[row];
    const float4* xr = (const float4*)(x + src * 2048);
    float4 a = xr[threadIdx.x * 2 + 0];
    float4 b = xr[threadIdx.x * 2 + 1];
    uint4 o;
    o.x = (unsigned)f2bs(a.x) | ((unsigned)f2bs(a.y) << 16);
    o.y = (unsigned)f2bs(a.z) | ((unsigned)f2bs(a.w) << 16);
    o.z = (unsigned)f2bs(b.x) | ((unsigned)f2bs(b.y) << 16);
    o.w = (unsigned)f2bs(b.z) | ((unsigned)f2bs(b.w) << 16);
    ((uint4*)(xg + (long)row * 2048))[threadIdx.x] = o;
}

// ---------------- transpose+cast weights: Wt[n][k] = bf16(W[k][n]) ----------------
__global__ void k_transpose(const float* __restrict__ W, unsigned short* __restrict__ Wt,
                            int K, int N, int Npad) {
    __shared__ float tile[32][33];
    const int n0 = blockIdx.x * 32, k0 = blockIdx.y * 32;
    const int tx = threadIdx.x, ty = threadIdx.y;   // 32 x 8
    #pragma unroll
    for (int i = 0; i < 32; i += 8) {
        int n = n0 + tx, k = k0 + ty + i;
        tile[ty + i][tx] = (n < N) ? W[(long)k * N + n] : 0.f;
    }
    __syncthreads();
    #pragma unroll
    for (int i = 0; i < 32; i += 8) {
        int n = n0 + ty + i, k = k0 + tx;
        if (n < Npad) Wt[(long)n * K + k] = f2bs(tile[tx][ty + i]);
    }
}

// ================= 256x256 deep-pipelined bf16 GEMM =================
// BK=32, 4 LDS K-tile buffers (128 KiB), prefetch distance 2, counted vmcnt(8)
// (never drains in main loop), raw s_barrier once per K-tile, setprio around
// MFMA cluster. LDS layout per tile: row j (0..127), slot s (8 x 16B) holds
// tile-row r = j + 128*h, 16B col-block c where (c+4h) = s ^ (j&7)  -> every
// ds_read_b128 spreads uniformly over all 32 banks. Optional fused BN stats.
template <int RELU, int STATS>
__global__ __launch_bounds__(512, 2) void k_gemm256(
    const unsigned short* __restrict__ A,
    const unsigned short* __restrict__ Bt,
    const float* __restrict__ bias,
    unsigned short* __restrict__ C,
    float* __restrict__ stats,
    int N, int K) {
    __shared__ unsigned short L[4 * 16384];   // 128 KiB: 4 bufs x (A 16K + B 16K) shorts
    const int tid  = threadIdx.x;
    const int lane = tid & 63;
    const int wv   = tid >> 6;       // 8 waves
    const int frow = lane & 15;
    const int kg   = lane >> 4;
    const int wr   = wv >> 2;        // M half (0..1)
    const int wcq  = wv & 3;         // N quarter (0..3)
    const int sA = (kg + 4 * wr) ^ (frow & 7);
    const int sB = (kg + 4 * (wcq >> 1)) ^ (frow & 7);

    // XCD-aware block swizzle: XCD x owns M-blocks 4x..4x+3, sweeps N-blocks.
    const int id  = blockIdx.x;
    const int xcd = id & 7, kid = id >> 3;
    const int brow = (xcd * 4 + (kid & 3)) * 256;
    const int bcol = (kid >> 2) * 256;

    // per-thread staging sources (2 A-slots + 2 B-slots, 16B each per K-tile)
    const unsigned short* pA[2];
    const unsigned short* pB[2];
    #pragma unroll
    for (int i = 0; i < 2; i++) {
        const int q = tid + i * 512;
        const int j = q >> 3;
        const int u = (q & 7) ^ (j & 7);
        const int r = j + 128 * (u >> 2);
        const int c = u & 3;
        pA[i] = A  + (long)(brow + r) * K + c * 8;
        pB[i] = Bt + (long)(bcol + r) * K + c * 8;
    }

    f32x4 acc[8][4];
    #pragma unroll
    for (int m = 0; m < 8; m++)
        #pragma unroll
        for (int n = 0; n < 4; n++)
            #pragma unroll
            for (int r = 0; r < 4; r++) acc[m][n][r] = 0.f;

    auto stage = [&](int tt) {
        unsigned short* Lb = &L[(tt & 3) * 16384];
        const int ko = tt * 32;
        GLD16(pA[0] + ko, Lb + wv * 512);
        GLD16(pA[1] + ko, Lb + 4096 + wv * 512);
        GLD16(pB[0] + ko, Lb + 8192 + wv * 512);
        GLD16(pB[1] + ko, Lb + 12288 + wv * 512);
    };
    auto compute = [&](int tt) {
        const unsigned short* A_ = &L[(tt & 3) * 16384];
        const unsigned short* B_ = A_ + 8192;
        bf16x8 av[8], bv[4];
        #pragma unroll
        for (int m = 0; m < 8; m++)
            av[m] = *(const bf16x8*)&A_[(m * 16 + frow) * 64 + sA * 8];
        #pragma unroll
        for (int n = 0; n < 4; n++)
            bv[n] = *(const bf16x8*)&B_[((wcq & 1) * 64 + n * 16 + frow) * 64 + sB * 8];
        __builtin_amdgcn_s_setprio(1);
        #pragma unroll
        for (int n = 0; n < 4; n++)
            #pragma unroll
            for (int m = 0; m < 8; m++)
                acc[m][n] = __builtin_amdgcn_mfma_f32_16x16x32_bf16(av[m], bv[n],
                                                                    acc[m][n], 0, 0, 0);
        __builtin_amdgcn_s_setprio(0);
    };

    const int nt = K >> 5;                 // 64 K-tiles for K=2048
    stage(0); stage(1); stage(2);          // 12 loads out
    asm volatile("s_waitcnt vmcnt(8)" ::: "memory");   // tile 0 landed
    __builtin_amdgcn_s_barrier();
    for (int t = 0; t < nt - 3; t++) {
        stage(t + 3);                       // 12 loads out again
        compute(t);
        asm volatile("s_waitcnt vmcnt(8)" ::: "memory");  // tile t+1 landed
        __builtin_amdgcn_s_barrier();
    }
    compute(nt - 3);
    asm volatile("s_waitcnt vmcnt(4)" ::: "memory");
    __builtin_amdgcn_s_barrier();
    compute(nt - 2);
    asm volatile("s_waitcnt vmcnt(0)" ::: "memory");
    __builtin_amdgcn_s_barrier();
    compute(nt - 1);

    // epilogue: bias (+relu) + bf16 store, optional fused BN column stats
    const int r0 = brow + wr * 128 + (lane >> 4) * 4;
    const int c0 = bcol + wcq * 64 + frow;
    #pragma unroll
    for (int n = 0; n < 4; n++) {
        const int col = c0 + n * 16;
        const float bb = bias[col];
        float s = 0.f, sq = 0.f;
        #pragma unroll
        for (int m = 0; m < 8; m++)
            #pragma unroll
            for (int r = 0; r < 4; r++) {
                const int row = r0 + m * 16 + r;
                float v = acc[m][n][r] + bb;
                if (STATS) { s += v; sq += v * v; }
                if (RELU) v = fmaxf(v, 0.f);
                C[(long)row * N + col] = f2bs(v);
            }
        if (STATS) {
            s += __shfl_xor(s, 16); sq += __shfl_xor(sq, 16);
            s += __shfl_xor(s, 32); sq += __shfl_xor(sq, 32);
            if (lane < 16) {
                atomicAdd(&stats[col], s);
                atomicAdd(&stats[N + col], sq);
            }
        }
    }
}

// ---------------- old 128x128 GEMM (classifier, f32 out) ----------------
template <int RELU, int F32OUT>
__global__ __launch_bounds__(256) void k_gemm(const unsigned short* __restrict__ A,
                                              const unsigned short* __restrict__ Bt,
                                              const float* __restrict__ bias,
                                              unsigned short* __restrict__ Cb,
                                              float* __restrict__ Cf,
                                              int M, int N, int K, int ldc) {
    constexpr int BK = 64;
    __shared__ unsigned short As[128 * BK];
    __shared__ unsigned short Bs[128 * BK];
    const int tid  = threadIdx.x;
    const int lane = tid & 63;
    const int wv   = tid >> 6;
    const int brow = blockIdx.x * 128;
    const int bcol = blockIdx.y * 128;
    const int wr   = (wv >> 1) * 64;
    const int wc   = (wv & 1) * 64;
    const int frow = lane & 15;
    const int kg   = lane >> 4;
    const int rx   = frow & 7;
    const int srow  = lane >> 3;
    const int sslot = (lane & 7) ^ srow;

    f32x4 acc[4][4];
    #pragma unroll
    for (int m = 0; m < 4; m++)
        #pragma unroll
        for (int n = 0; n < 4; n++)
            #pragma unroll
            for (int r = 0; r < 4; r++) acc[m][n][r] = 0.f;

    for (int kt = 0; kt < K; kt += BK) {
        #pragma unroll
        for (int i = 0; i < 4; i++) {
            const int c = wv * 4 + i;
            const int r = c * 8 + srow;
            GLD16(A + (long)(brow + r) * K + kt + sslot * 8, &As[c * 512]);
        }
        #pragma unroll
        for (int i = 0; i < 4; i++) {
            const int c = wv * 4 + i;
            const int r = c * 8 + srow;
            GLD16(Bt + (long)(bcol + r) * K + kt + sslot * 8, &Bs[c * 512]);
        }
        __syncthreads();
        #pragma unroll
        for (int kk = 0; kk < 2; kk++) {
            bf16x8 av[4], bv[4];
            #pragma unroll
            for (int m = 0; m < 4; m++) {
                const int row = wr + m * 16 + frow;
                av[m] = *(const bf16x8*)&As[row * BK + (((kk * 4 + kg) ^ rx) * 8)];
            }
            #pragma unroll
            for (int n = 0; n < 4; n++) {
                const int row = wc + n * 16 + frow;
                bv[n] = *(const bf16x8*)&Bs[row * BK + (((kk * 4 + kg) ^ rx) * 8)];
            }
            #pragma unroll
            for (int m = 0; m < 4; m++)
                #pragma unroll
                for (int n = 0; n < 4; n++)
                    acc[m][n] = __builtin_amdgcn_mfma_f32_16x16x32_bf16(av[m], bv[n],
                                                                        acc[m][n], 0, 0, 0);
        }
        __syncthreads();
    }
    const int r0 = brow + wr + (lane >> 4) * 4;
    const int c0 = bcol + wc + (lane & 15);
    #pragma unroll
    for (int n = 0; n < 4; n++) {
        const int col = c0 + n * 16;
        if (col < N) {
            const float bb = bias[col];
            #pragma unroll
            for (int m = 0; m < 4; m++) {
                #pragma unroll
                for (int r = 0; r < 4; r++) {
                    const int row = r0 + m * 16 + r;
                    float v = acc[m][n][r] + bb;
                    if (RELU) v = fmaxf(v, 0.f);
                    if (F32OUT) Cf[(long)row * ldc + col] = v;
                    else        Cb[(long)row * ldc + col] = f2bs(v);
                }
            }
        }
    }
}

// ---------------- BatchNorm: finalize / apply ----------------
__global__ void k_bnfin(float* __restrict__ sums, const float* __restrict__ g,
                        const float* __restrict__ be, int ncols) {
    const int c = blockIdx.x * blockDim.x + threadIdx.x;
    const float m   = sums[c] * (1.f / NB);
    const float var = sums[ncols + c] * (1.f / NB) - m * m;
    const float sc  = rsqrtf(var + EPSV) * g[c];
    sums[c] = sc;
    sums[ncols + c] = be[c] - m * sc;
}

template <int RELU>
__global__ void k_bnapply(unsigned short* __restrict__ t, const float* __restrict__ sums,
                          int ncols) {
    const long i  = ((long)blockIdx.x * blockDim.x + threadIdx.x) * 8;
    const int  c0 = (int)(i & (ncols - 1));
    uint4 v = *(uint4*)(t + i);
    unsigned int us[8] = {v.x & 0xffffu, v.x >> 16, v.y & 0xffffu, v.y >> 16,
                          v.z & 0xffffu, v.z >> 16, v.w & 0xffffu, v.w >> 16};
    unsigned int po[8];
    #pragma unroll
    for (int j = 0; j < 8; j++) {
        const int c = c0 + j;
        float val = bs2f(us[j]) * sums[c] + sums[ncols + c];
        if (RELU) val = fmaxf(val, 0.f);
        po[j] = f2bs(val);
    }
    uint4 o;
    o.x = po[0] | (po[1] << 16); o.y = po[2] | (po[3] << 16);
    o.z = po[4] | (po[5] << 16); o.w = po[6] | (po[7] << 16);
    *(uint4*)(t + i) = o;
}

// ---------------- logit losses ----------------
__global__ __launch_bounds__(256) void k_logitloss(const float* __restrict__ out,
                            const int* __restrict__ y,
                            const int* __restrict__ order, const int* __restrict__ s1,
                            const int* __restrict__ s2, const float* __restrict__ lamp,
                            float* __restrict__ acc) {
    const int lane = threadIdx.x & 63;
    const int wv   = threadIdx.x >> 6;
    const int wid  = blockIdx.x * 4 + wv;
    const int nw   = gridDim.x * 4;
    const float lam = lamp[0];
    float ce = 0.f, d1 = 0.f, d2 = 0.f;
    for (int i = wid; i < NB; i += nw) {
        const float* o  = out + (long)i * NCP;
        const float* o2 = out + (long)s1[i] * NCP;
        const float* o3 = out + (long)s2[i] * NCP;
        float v[6];
        float mx = -1e30f;
        #pragma unroll
        for (int j = 0; j < 6; j++) {
            const int c = lane + j * 64;
            if (c < NC) {
                const float a = o[c], b = o2[c], cc = o3[c];
                const float mix = lam * b + (1.f - lam) * cc;
                v[j] = a;
                d1 += (a - b) * (a - b);
                d2 += (a - mix) * (a - mix);
                mx = fmaxf(mx, a);
            } else v[j] = -1e30f;
        }
        #pragma unroll
        for (int off = 32; off; off >>= 1) mx = fmaxf(mx, __shfl_xor(mx, off));
        float se = 0.f;
        #pragma unroll
        for (int j = 0; j < 6; j++) se += expf(v[j] - mx);
        #pragma unroll
        for (int off = 32; off; off >>= 1) se += __shfl_xor(se, off);
        if (lane == 0) {
            const int yv = y[order[i]];
            ce += mx + logf(se) - o[yv];
        }
    }
    #pragma unroll
    for (int off = 32; off; off >>= 1) {
        d1 += __shfl_xor(d1, off);
        d2 += __shfl_xor(d2, off);
    }
    __shared__ float red[4][3];
    if (lane == 0) { red[wv][0] = ce; red[wv][1] = d1; red[wv][2] = d2; }
    __syncthreads();
    if (threadIdx.x == 0) {
        atomicAdd(&acc[0], red[0][0] + red[1][0] + red[2][0] + red[3][0]);
        atomicAdd(&acc[1], red[0][1] + red[1][1] + red[2][1] + red[3][1]);
        atomicAdd(&acc[2], red[0][2] + red[1][2] + red[2][2] + red[3][2]);
    }
}

// ---------------- proj feature losses (BN applied inline from stats) ----------------
__global__ __launch_bounds__(256) void k_featloss(const unsigned short* __restrict__ t3,
                           const float* __restrict__ st,
                           const int* __restrict__ s1,
                           const int* __restrict__ s2, const float* __restrict__ lamp,
                           float* __restrict__ acc) {
    const int t = threadIdx.x;   // 256, cols t*8..t*8+7
    const float lam = lamp[0];
    float sc[8], sh[8];
    #pragma unroll
    for (int j = 0; j < 8; j++) { sc[j] = st[t * 8 + j]; sh[j] = st[NF + t * 8 + j]; }
    float d1 = 0.f, d2 = 0.f;
    for (int i = blockIdx.x; i < NB; i += gridDim.x) {
        uint4 a = ((const uint4*)(t3 + (long)i * NF))[t];
        uint4 b = ((const uint4*)(t3 + (long)s1[i] * NF))[t];
        uint4 c = ((const uint4*)(t3 + (long)s2[i] * NF))[t];
        unsigned int ua[8] = {a.x & 0xffffu, a.x >> 16, a.y & 0xffffu, a.y >> 16,
                              a.z & 0xffffu, a.z >> 16, a.w & 0xffffu, a.w >> 16};
        unsigned int ub[8] = {b.x & 0xffffu, b.x >> 16, b.y & 0xffffu, b.y >> 16,
                              b.z & 0xffffu, b.z >> 16, b.w & 0xffffu, b.w >> 16};
        unsigned int uc[8] = {c.x & 0xffffu, c.x >> 16, c.y & 0xffffu, c.y >> 16,
                              c.z & 0xffffu, c.z >> 16, c.w & 0xffffu, c.w >> 16};
        #pragma unroll
        for (int j = 0; j < 8; j++) {
            float pa = sc[j] * bs2f(ua[j]) + sh[j];
            float pb = sc[j] * bs2f(ub[j]) + sh[j];
            float pc = sc[j] * bs2f(uc[j]) + sh[j];
            float mix = lam * pb + (1.f - lam) * pc;
            d1 += (pa - pb) * (pa - pb);
            d2 += (pa - mix) * (pa - mix);
        }
    }
    #pragma unroll
    for (int off = 32; off; off >>= 1) {
        d1 += __shfl_xor(d1, off);
        d2 += __shfl_xor(d2, off);
    }
    __shared__ float r1[4], r2[4];
    if ((t & 63) == 0) { r1[t >> 6] = d1; r2[t >> 6] = d2; }
    __syncthreads();
    if (t == 0) {
        atomicAdd(&acc[3], r1[0] + r1[1] + r1[2] + r1[3]);
        atomicAdd(&acc[4], r2[0] + r2[1] + r2[2] + r2[3]);
    }
}

__global__ void k_final(const float* __restrict__ acc, const float* __restrict__ lamp,
                        float* __restrict__ outp) {
    const float lam = lamp[0];
    const float cl  = acc[0] * (1.f / NB);
    const float Lil = acc[1] * (1.f / ((float)NB * NC));
    const float Lhl = acc[2] * (1.f / ((float)NB * NC));
    const float Lif = 0.3f * acc[3] * (1.f / ((float)NB * NF));
    const float Lhf = 0.3f * acc[4] * (1.f / ((float)NB * NF));
    const float Cs  = fminf(cl, 1.f);
    outp[0] = cl + Cs * (lam * (Lil + Lif) + (1.f - lam) * (Lhl + Lhf));
}

extern "C" void kernel_launch(void* const* d_in, const int* in_sizes, int n_in,
                              void* d_out, int out_size, void* d_ws, size_t ws_size,
                              hipStream_t stream) {
    const float* x   = (const float*)d_in[0];
    const float* lam = (const float*)d_in[1];
    const float* Wf  = (const float*)d_in[2];
    const float* bf_ = (const float*)d_in[3];
    const float* W1  = (const float*)d_in[4];
    const float* b1  = (const float*)d_in[5];
    const float* g1  = (const float*)d_in[6];
    const float* be1 = (const float*)d_in[7];
    const float* W2  = (const float*)d_in[8];
    const float* b2  = (const float*)d_in[9];
    const float* g2  = (const float*)d_in[10];
    const float* be2 = (const float*)d_in[11];
    const float* W3  = (const float*)d_in[12];
    const float* b3  = (const float*)d_in[13];
    const float* g3  = (const float*)d_in[14];
    const float* be3 = (const float*)d_in[15];
    const float* Wc  = (const float*)d_in[16];
    const float* bc  = (const float*)d_in[17];
    const int* y     = (const int*)d_in[18];
    const int* order = (const int*)d_in[19];
    const int* s1    = (const int*)d_in[20];
    const int* s2    = (const int*)d_in[21];
    float* outp = (float*)d_out;

    char* ws = (char*)d_ws;
    const size_t SZ_ACT = (size_t)NB * 2048 * 2;                    // 32 MiB
    unsigned short* bufA = (unsigned short*)(ws);                   // xg -> t2/h2
    unsigned short* bufB = (unsigned short*)(ws + SZ_ACT);          // feat -> t3
    unsigned short* bufC = (unsigned short*)(ws + 2 * SZ_ACT);      // t1/h1
    float* outbuf = (float*)(ws + 3 * SZ_ACT);                      // 8192 x 384 f32
    size_t off = 3 * SZ_ACT + (size_t)NB * NCP * 4;
    unsigned short* WT0 = (unsigned short*)(ws + off); off += (size_t)2048 * 2048 * 2;
    unsigned short* WT1 = (unsigned short*)(ws + off); off += (size_t)2048 * 2048 * 2;
    unsigned short* WT2 = (unsigned short*)(ws + off); off += (size_t)2048 * 2048 * 2;
    unsigned short* WT3 = (unsigned short*)(ws + off); off += (size_t)2048 * 2048 * 2;
    unsigned short* WCT = (unsigned short*)(ws + off); off += (size_t)NCP * 2048 * 2;
    float* stats = (float*)(ws + off);                               // 3 x 4096 floats
    float* accs  = stats + 3 * 4096;                                 // 5 floats used

    hipMemsetAsync(stats, 0, (3 * 4096 + 8) * sizeof(float), stream);

    dim3 tb(32, 8);
    k_transpose<<<dim3(64, 64), tb, 0, stream>>>(Wf, WT0, 2048, 2048, 2048);
    k_transpose<<<dim3(64, 64), tb, 0, stream>>>(W1, WT1, 2048, 2048, 2048);
    k_transpose<<<dim3(64, 64), tb, 0, stream>>>(W2, WT2, 2048, 2048, 2048);
    k_transpose<<<dim3(64, 64), tb, 0, stream>>>(W3, WT3, 2048, 2048, 2048);
    k_transpose<<<dim3(12, 64), tb, 0, stream>>>(Wc, WCT, 2048, NC, NCP);

    k_gather<<<NB, 256, 0, stream>>>(x, order, bufA);

    // feat = relu(xg @ Wf + bf)
    k_gemm256<1, 0><<<256, 512, 0, stream>>>(bufA, WT0, bf_, bufB, nullptr, 2048, 2048);
    // out = feat @ Wc + bc   (f32, ldc=384) — old 128x128 kernel
    k_gemm<0, 1><<<dim3(64, 3), 256, 0, stream>>>(bufB, WCT, bc, nullptr, outbuf, NB, NC, 2048, NCP);
    // t1 = feat @ W1 + b1 (+ fused BN stats) ; h1 = relu(bn(t1))
    k_gemm256<0, 1><<<256, 512, 0, stream>>>(bufB, WT1, b1, bufC, stats, 2048, 2048);
    k_bnfin<<<8, 256, 0, stream>>>(stats, g1, be1, 2048);
    k_bnapply<1><<<8192, 256, 0, stream>>>(bufC, stats, 2048);
    // t2 = h1 @ W2 + b2 (+ stats) ; h2 = relu(bn(t2))
    k_gemm256<0, 1><<<256, 512, 0, stream>>>(bufC, WT2, b2, bufA, stats + 4096, 2048, 2048);
    k_bnfin<<<8, 256, 0, stream>>>(stats + 4096, g2, be2, 2048);
    k_bnapply<1><<<8192, 256, 0, stream>>>(bufA, stats + 4096, 2048);
    // t3 = h2 @ W3 + b3 (+ stats) ; proj consumed directly by featloss
    k_gemm256<0, 1><<<256, 512, 0, stream>>>(bufA, WT3, b3, bufB, stats + 8192, 2048, 2048);
    k_bnfin<<<8, 256, 0, stream>>>(stats + 8192, g3, be3, 2048);

    k_logitloss<<<256, 256, 0, stream>>>(outbuf, y, order, s1, s2, lam, accs);
    k_featloss<<<512, 256, 0, stream>>>(bufB, stats + 8192, s1, s2, lam, accs);
    k_final<<<1, 1, 0, stream>>>(accs, lam, outp);
}